// Round 4
// baseline (344.248 us; speedup 1.0000x reference)
//
#include <hip/hip_runtime.h>

#define NN 512
#define CC 1024
#define OO 256
#define VV 68
#define PP 7
#define NC (NN*CC)
#define NV_CNT 34816.0f   // N*T*V = 512*68

__device__ __forceinline__ int part_of(int v){
  return (v>=17)+(v>=22)+(v>=27)+(v>=36)+(v>=42)+(v>=48);
}

// K0: repack w1 [o][c] -> w1p[cb][o] (float4 units). Coalesced READ
// (g walks w1 linearly); scattered writes are fire-and-forget.
__global__ __launch_bounds__(256) void k0_repack(const float* __restrict__ w1,
    float* __restrict__ w1p){
  int g = blockIdx.x*256 + threadIdx.x;          // f4 idx in w1: g = o*256+cb
  int o = g >> 8, cb = g & 255;
  float4 v = ((const float4*)w1)[g];
  ((float4*)w1p)[cb*256 + o] = v;
}

// K1: direct per-row part sums over V=68. Thread = row (n*C+c).
// 17 independent float4 loads; lane-consecutive rows are 272B apart but each
// 64B line is read exactly once program-wide (L1 serves 3/4 of the f4 hits).
__global__ __launch_bounds__(256) void k1_partsum(const float* __restrict__ x,
    float* __restrict__ S, float* __restrict__ S2){
  int r = blockIdx.x*256 + threadIdx.x;
  const float4* xr = (const float4*)(x + (size_t)r*VV);
  float s[PP], q[PP];
  #pragma unroll
  for (int p=0;p<PP;p++){ s[p]=0.f; q[p]=0.f; }
  #pragma unroll
  for (int i=0;i<17;i++){
    float4 v4 = xr[i];
    #pragma unroll
    for (int j=0;j<4;j++){
      int p = part_of(i*4+j);                    // folds to constant
      float e = (j==0)?v4.x:(j==1)?v4.y:(j==2)?v4.z:v4.w;
      s[p] += e;
      q[p] = fmaf(e, e, q[p]);
    }
  }
  #pragma unroll
  for (int p=0;p<PP;p++){
    S [p*NC + r] = s[p];
    S2[p*NC + r] = q[p];
  }
}

// K2 fused: one block per n. Thread t: oh=t&31, ch=t>>5 (8 c-eighths of 128c).
// Each thread: 8 o's (oh+32k) x its 128 c. S row staged in LDS; sv reads are
// 2-address broadcasts (same banks, 2-way = free). 224 FMA per 7 LDS reads.
// Then in-block reduce over ch, mean/max over o, softmax over p -> att[n].
__global__ __launch_bounds__(256) void k2_att(const float* __restrict__ S,
    const float* __restrict__ w1p, const float* __restrict__ b1,
    const float* __restrict__ w2, const float* __restrict__ b2,
    float* __restrict__ att){
  int n = blockIdx.x;
  int t = threadIdx.x;
  int oh = t & 31, ch = t >> 5;

  __shared__ float4 sf[PP*256];                  // 28672 B
  for (int u = t; u < PP*256; u += 256){
    int p = u >> 8, cb = u & 255;
    sf[u] = *(const float4*)(S + (size_t)p*NC + (size_t)n*CC + cb*4);
  }
  __syncthreads();

  float acc[8][PP];
  #pragma unroll
  for (int k=0;k<8;k++)
    #pragma unroll
    for (int p=0;p<PP;p++) acc[k][p] = 0.f;

  const float4* wp = (const float4*)w1p;
  for (int i=0;i<32;i++){
    int gcb = ch*32 + i;
    const float4* wrow = wp + (size_t)gcb*256 + oh;
    float4 w[8];
    #pragma unroll
    for (int k=0;k<8;k++) w[k] = wrow[32*k];
    #pragma unroll
    for (int p=0;p<PP;p++){
      float4 sv = sf[p*256 + gcb];
      #pragma unroll
      for (int k=0;k<8;k++){
        acc[k][p] = fmaf(w[k].x, sv.x, acc[k][p]);
        acc[k][p] = fmaf(w[k].y, sv.y, acc[k][p]);
        acc[k][p] = fmaf(w[k].z, sv.z, acc[k][p]);
        acc[k][p] = fmaf(w[k].w, sv.w, acc[k][p]);
      }
    }
  }

  // reduce over ch: h[o=k*32+oh] = sum_ch acc ; o for this thread = t.
  const float inv_cnt[PP] = {1.f/17.f,1.f/5.f,1.f/5.f,1.f/9.f,1.f/6.f,1.f/6.f,1.f/20.f};
  float* sfl = (float*)sf;                       // reuse staging LDS (8 KB used)
  float bo = b1[t];
  float h[PP];
  #pragma unroll
  for (int p=0;p<PP;p++){
    __syncthreads();
    #pragma unroll
    for (int k=0;k<8;k++) sfl[ch*256 + k*32 + oh] = acc[k][p];
    __syncthreads();
    float hs = 0.f;
    #pragma unroll
    for (int c8=0;c8<8;c8++) hs += sfl[c8*256 + t];
    h[p] = fmaf(hs, inv_cnt[p], bo);
  }

  __shared__ float red_s[4][PP];
  __shared__ float red_m[4][PP];
  __shared__ float pre[PP];
  int lane = t & 63, wid = t >> 6;
  #pragma unroll
  for (int p=0;p<PP;p++){
    float sm = h[p], mx = h[p];
    #pragma unroll
    for (int off=32; off>0; off>>=1){
      sm += __shfl_down(sm, off, 64);
      mx = fmaxf(mx, __shfl_down(mx, off, 64));
    }
    if (lane==0){ red_s[wid][p]=sm; red_m[wid][p]=mx; }
  }
  __syncthreads();
  if (t < PP){
    int p = t;
    float sm = red_s[0][p]+red_s[1][p]+red_s[2][p]+red_s[3][p];
    float mx = fmaxf(fmaxf(red_m[0][p],red_m[1][p]),
                     fmaxf(red_m[2][p],red_m[3][p]));
    pre[p] = w2[0]*(sm*(1.f/(float)OO)) + w2[1]*mx + b2[0];
  }
  __syncthreads();
  if (t == 0){
    float m = pre[0];
    #pragma unroll
    for (int p=1;p<PP;p++) m = fmaxf(m, pre[p]);
    float e[PP], sum=0.f;
    #pragma unroll
    for (int p=0;p<PP;p++){ e[p] = expf(pre[p]-m); sum += e[p]; }
    float inv = 1.f/sum;
    #pragma unroll
    for (int p=0;p<PP;p++) att[n*PP+p] = e[p]*inv;
  }
}

// K3: partial BN sums per channel. 512 blocks = 4 c-blocks x 128 n-chunks (4 n each).
__global__ __launch_bounds__(256) void k3_stats(const float* __restrict__ S,
    const float* __restrict__ S2, const float* __restrict__ att,
    float* __restrict__ partial){
  int cb  = blockIdx.x & 3;
  int nch = blockIdx.x >> 2;                     // 0..127
  int c = cb*256 + threadIdx.x;
  float sm=0.f, sq=0.f;
  for (int i=0;i<4;i++){
    int n = nch*4 + i;
    #pragma unroll
    for (int p=0;p<PP;p++){
      float a = att[n*PP+p];                     // wave-uniform
      sm = fmaf(a,   S [p*NC + n*CC + c], sm);
      sq = fmaf(a*a, S2[p*NC + n*CC + c], sq);
    }
  }
  partial[nch*2*CC + c]      = sm;
  partial[nch*2*CC + CC + c] = sq;
}

// K3b: finalize mean/var -> scale/shift per channel.
__global__ __launch_bounds__(256) void k3b_finalize(const float* __restrict__ partial,
    const float* __restrict__ gamma, const float* __restrict__ beta,
    float* __restrict__ scsh){
  int c = blockIdx.x*256 + threadIdx.x;
  float sm=0.f, sq=0.f;
  for (int ch=0;ch<128;ch++){
    sm += partial[ch*2*CC + c];
    sq += partial[ch*2*CC + CC + c];
  }
  float mean = sm * (1.0f/NV_CNT);
  float msq  = sq * (1.0f/NV_CNT);
  float var  = msq - mean*mean;
  float rstd = rsqrtf(var + 1e-5f);
  float sc = gamma[c]*rstd;
  scsh[c]      = sc;
  scsh[CC + c] = beta[c] - mean*sc;
}

// K4: out = relu( x*(att_j*scale + 1) + shift ), float4 over flat index.
__global__ __launch_bounds__(256) void k4_out(const float* __restrict__ x,
    const float* __restrict__ att, const float* __restrict__ scsh,
    float* __restrict__ out){
  int f = blockIdx.x*256 + threadIdx.x;          // float4 index, < NC*17
  int n = blockIdx.x / 68;                       // uniform within block
  __shared__ float s_att[PP];
  if (threadIdx.x < PP) s_att[threadIdx.x] = att[n*PP + threadIdx.x];
  __syncthreads();
  int r = f/17;
  int q = f - r*17;
  int v0 = q*4;
  int c = r & (CC-1);
  float4 xv = ((const float4*)x)[f];
  float sc = scsh[c];
  float sh = scsh[CC + c];
  float vals[4];
  #pragma unroll
  for (int j=0;j<4;j++){
    int p = part_of(v0 + j);
    float a = s_att[p];
    float e = (j==0)?xv.x:(j==1)?xv.y:(j==2)?xv.z:xv.w;
    vals[j] = fmaxf(fmaf(e, fmaf(a, sc, 1.0f), sh), 0.0f);
  }
  float4 ov; ov.x=vals[0]; ov.y=vals[1]; ov.z=vals[2]; ov.w=vals[3];
  ((float4*)out)[f] = ov;
}

extern "C" void kernel_launch(void* const* d_in, const int* in_sizes, int n_in,
                              void* d_out, int out_size, void* d_ws, size_t ws_size,
                              hipStream_t stream) {
  const float* x     = (const float*)d_in[0];
  const float* w1    = (const float*)d_in[1];
  const float* b1    = (const float*)d_in[2];
  const float* w2    = (const float*)d_in[3];
  const float* b2    = (const float*)d_in[4];
  const float* gamma = (const float*)d_in[5];
  const float* beta  = (const float*)d_in[6];
  float* out = (float*)d_out;

  float* S       = (float*)d_ws;                 // 7*NC
  float* S2      = S  + 7*NC;                    // 7*NC
  float* att     = S2 + 7*NC;                    // 512*7
  float* partial = att + NN*PP;                  // 128*2*1024
  float* scsh    = partial + 128*2*CC;           // 2*1024
  float* w1p     = scsh + 2*CC;                  // 256*1024 (1 MB)
  // total ~31 MB of ws

  k0_repack   <<<256,         256, 0, stream>>>(w1, w1p);
  k1_partsum  <<<NC/256,      256, 0, stream>>>(x, S, S2);
  k2_att      <<<NN,          256, 0, stream>>>(S, w1p, b1, w2, b2, att);
  k3_stats    <<<512,         256, 0, stream>>>(S, S2, att, partial);
  k3b_finalize<<<CC/256,      256, 0, stream>>>(partial, gamma, beta, scsh);
  k4_out      <<<(NC*17)/256, 256, 0, stream>>>(x, att, scsh, out);
}